// Round 3
// baseline (495.303 us; speedup 1.0000x reference)
//
#include <hip/hip_runtime.h>
#include <stdint.h>

#define M_DIM 4096
#define K_DIM 4096
#define N_DIM 11008

typedef int v4i __attribute__((ext_vector_type(4)));

// Address-space casts via uintptr_t (composable_kernel pattern).
#define LDSP(p) ((__attribute__((address_space(3))) void*)(uintptr_t)(p))
#define GLBP(p) ((__attribute__((address_space(1))) void*)(uintptr_t)(p))

// ---------------------------------------------------------------------------
// Kernel 1: per-row dynamic quantization of x (fp32 -> int8) + row scale.
// ---------------------------------------------------------------------------
__global__ __launch_bounds__(256) void quant_rows(const float* __restrict__ x,
                                                  int8_t* __restrict__ xq,
                                                  float* __restrict__ xs_out) {
    const int row = blockIdx.x;
    const int t = threadIdx.x;
    const float4* xr = (const float4*)(x + (size_t)row * K_DIM);

    float4 v[4];
    float amax = 0.0f;
#pragma unroll
    for (int r = 0; r < 4; ++r) {
        v[r] = xr[t + r * 256];
        amax = fmaxf(amax, fmaxf(fmaxf(fabsf(v[r].x), fabsf(v[r].y)),
                                 fmaxf(fabsf(v[r].z), fabsf(v[r].w))));
    }
#pragma unroll
    for (int off = 32; off > 0; off >>= 1)
        amax = fmaxf(amax, __shfl_xor(amax, off));

    __shared__ float smax[4];
    if ((t & 63) == 0) smax[t >> 6] = amax;
    __syncthreads();
    amax = fmaxf(fmaxf(smax[0], smax[1]), fmaxf(smax[2], smax[3]));

    const float xs = fmaxf(amax / 127.0f, 1e-8f);
    if (t == 0) xs_out[row] = xs;

    int* qo = (int*)(xq + (size_t)row * K_DIM);
#pragma unroll
    for (int r = 0; r < 4; ++r) {
        int q0 = (int)rintf(v[r].x / xs);
        int q1 = (int)rintf(v[r].y / xs);
        int q2 = (int)rintf(v[r].z / xs);
        int q3 = (int)rintf(v[r].w / xs);
        q0 = min(127, max(-128, q0));
        q1 = min(127, max(-128, q1));
        q2 = min(127, max(-128, q2));
        q3 = min(127, max(-128, q3));
        int packed = (q0 & 255) | ((q1 & 255) << 8) | ((q2 & 255) << 16) | (q3 << 24);
        qo[t + r * 256] = packed;
    }
}

// ---------------------------------------------------------------------------
// Kernel 2: normalize weight into contiguous int8 in workspace (unchanged).
// ---------------------------------------------------------------------------
__global__ __launch_bounds__(256) void prep_weight(const void* __restrict__ wraw,
                                                   int8_t* __restrict__ w8) {
    const int* wi = (const int*)wraw;
    int c = 0;
#pragma unroll
    for (int i = 0; i < 64; ++i) {
        int w = wi[i];
        c += (w >= -128 && w <= 127) ? 1 : 0;
    }
    const size_t tid = (size_t)blockIdx.x * 256 + threadIdx.x;  // 16 bytes each
    if (c >= 32) {
        union { int4 v; char b[16]; } o;
#pragma unroll
        for (int g = 0; g < 4; ++g) {
            int4 w = ((const int4*)wraw)[tid * 4 + g];
            o.b[g * 4 + 0] = (char)w.x;
            o.b[g * 4 + 1] = (char)w.y;
            o.b[g * 4 + 2] = (char)w.z;
            o.b[g * 4 + 3] = (char)w.w;
        }
        ((int4*)w8)[tid] = o.v;
    } else {
        ((int4*)w8)[tid] = ((const int4*)wraw)[tid];
    }
}

// ---------------------------------------------------------------------------
// Kernel 3: int8 GEMM — 256x256 tile, BK=128, A-ring(3)/B-ring(2) = 160 KiB,
// now with 4 FINE PHASES per K-tile (16 MFMA + 4-8 ds_read each).
//
// Round-2 post-mortem: 2-phase/tile structure phase-serialized the LDS port
// (2300 cy/tile of ds_read) against the MFMA pipe (2480 cy/tile): measured
// 5300 cy/tile, MfmaUtil 43%. Fine phases stagger waves' lgkmcnt release so
// early waves' MFMAs overlap late waves' LDS reads (separate pipes), and
// give setprio a role-split to arbitrate.
//
// Per K-tile t (slots SA=t%3, SB=t%2; stage target SA2=(t+2)%3):
//   ph0: read bf[0-3](k0) + af[0-3](k0) | stage A(t+2) rows 0-127   | MFMA i0-3,k0
//   ph1: read af[4-7](k0)               | stage A(t+2) rows 128-255 | MFMA i4-7,k0
//   ph2: read bf[4-7](k1) + af[0-3](k1) | -                         | MFMA i0-3,k1
//   ph3: read af[4-7](k1)               | stage B(t+2); vmcnt(8)    | MFMA i4-7,k1
// Each phase: reads/stages, then {barrier; lgkmcnt(0); sched_barrier(0);
// setprio(1)}; 16 MFMA; {setprio(0); barrier}.
// Safety: A(t+2) slot retired at t-1's last PH_POST barrier. B(t+2) writes
// the slot read THIS tile — its stage sits after ph2's PH_POST, which follows
// ph2's lgkmcnt(0) drain of the final B reads in every wave. vmcnt(8) leaves
// exactly A(t+2)+B(t+2) in flight -> tile t+1 landed. Never vmcnt(0) in the
// loop; tiles 30/31 peeled (no stages, one vmcnt(0)).
// ---------------------------------------------------------------------------
__global__ __launch_bounds__(512, 2) void w8a8_gemm(const int8_t* __restrict__ xq,
                                                    const float* __restrict__ xscale,
                                                    const int8_t* __restrict__ wgt,
                                                    const float* __restrict__ wscale,
                                                    const float* __restrict__ bias,
                                                    float* __restrict__ out) {
    __shared__ __align__(16) int8_t lds_a[3][32768];  // 96 KB: A ring, 3 tiles
    __shared__ __align__(16) int8_t lds_b[2][32768];  // 64 KB: B ring, 2 tiles

    const int t = threadIdx.x;
    const int lane = t & 63;
    const int wave = t >> 6;   // 0..7
    const int wm = wave >> 2;  // 0..1  (M half)
    const int wn = wave & 3;   // 0..3  (N quarter)
    const int quad = lane >> 4;
    const int l15 = lane & 15;

    // XCD-aware swizzle, bm-fastest within chunk (688 = 8 XCDs x 86).
    const int wg = blockIdx.x;
    const int xcd = wg & 7;
    const int u = wg >> 3;              // 0..85 within XCD
    const int bm = 2 * xcd + (u & 1);   // each XCD owns a bm pair
    const int bn = u >> 1;              // 0..42

    const int8_t* pa = xq + (size_t)bm * 256 * K_DIM;
    const int8_t* pb = wgt + (size_t)bn * 256 * K_DIM;

    // Staging: thread t covers (row = g*64 + (t>>3), 16B-chunk = t&7); source
    // chunk pre-XOR'd so linear LDS write + XOR'd read = swizzle.
    const int srow = t >> 3;  // 0..63
    const size_t soff = (size_t)srow * K_DIM + (size_t)(((t & 7) ^ (srow & 7)) << 4);
    const size_t g64 = (size_t)64 * K_DIM;  // +64 rows

#define STAGE_HALF2(gb, lb)                                                                  \
    do {                                                                                     \
        __builtin_amdgcn_global_load_lds(GLBP((gb) + soff), LDSP((lb) + t * 16), 16, 0, 0);  \
        __builtin_amdgcn_global_load_lds(GLBP((gb) + soff + g64), LDSP((lb) + 8192 + t * 16), 16, 0, 0); \
    } while (0)
#define STAGE_TILE(gb, lb)                                                                   \
    do {                                                                                     \
        STAGE_HALF2(gb, lb);                                                                 \
        STAGE_HALF2((gb) + 2 * g64, (lb) + 16384);                                           \
    } while (0)

    // Fragment read offsets: row*128 + ((ks*4+quad) ^ (row&7))*16.
    int abase[2], bbase[2];
#pragma unroll
    for (int ks = 0; ks < 2; ++ks) {
        const int ar = wm * 128 + l15;
        abase[ks] = ar * 128 + (((ks * 4 + quad) ^ (l15 & 7)) << 4);
        const int br = wn * 64 + l15;
        bbase[ks] = br * 128 + (((ks * 4 + quad) ^ (l15 & 7)) << 4);
    }

    v4i acc[8][4] = {};
    v4i af[8], bf[8];  // bf[0-3]=k0, bf[4-7]=k1; af reused per k-step quadrants

#define READ_B4(SB, KS, B0)                                           \
    _Pragma("unroll") for (int j = 0; j < 4; ++j)                     \
        bf[(B0) + j] = *(const v4i*)(&lds_b[SB][bbase[KS] + j * 2048]);
#define READ_A4Q(SA, KS, I0)                                          \
    _Pragma("unroll") for (int i = 0; i < 4; ++i)                     \
        af[(I0) + i] = *(const v4i*)(&lds_a[SA][abase[KS] + ((I0) + i) * 2048]);
#define MFMAQ(I0, B0)                                                 \
    _Pragma("unroll") for (int i = 0; i < 4; ++i)                     \
    _Pragma("unroll") for (int j = 0; j < 4; ++j)                     \
        acc[(I0) + i][j] = __builtin_amdgcn_mfma_i32_16x16x64_i8(     \
            af[(I0) + i], bf[(B0) + j], acc[(I0) + i][j], 0, 0, 0);
#define PH_PRE                                                        \
    __builtin_amdgcn_s_barrier();                                     \
    asm volatile("s_waitcnt lgkmcnt(0)" ::: "memory");                \
    __builtin_amdgcn_sched_barrier(0);                                \
    __builtin_amdgcn_s_setprio(1);
#define PH_POST                                                       \
    __builtin_amdgcn_s_setprio(0);                                    \
    __builtin_amdgcn_s_barrier();

    // ---- prologue: stage tiles 0,1 (A slots 0,1 / B slots 0,1) ----
    STAGE_TILE(pa, &lds_a[0][0]);
    STAGE_TILE(pb, &lds_b[0][0]);
    STAGE_TILE(pa + 128, &lds_a[1][0]);
    STAGE_TILE(pb + 128, &lds_b[1][0]);
    asm volatile("s_waitcnt vmcnt(8)" ::: "memory");  // tile 0 (oldest 8) landed
    __builtin_amdgcn_s_barrier();

#define DO_TILE(U)                                                       \
    {                                                                    \
        constexpr int SA = (U) % 3;                                      \
        constexpr int SB = (U) % 2;                                      \
        constexpr int SA2 = ((U) + 2) % 3;                               \
        const size_t k2 = (size_t)(t0 + (U) + 2) * 128;                  \
        /* ph0 */                                                        \
        READ_B4(SB, 0, 0);                                               \
        READ_A4Q(SA, 0, 0);                                              \
        STAGE_HALF2(pa + k2, &lds_a[SA2][0]);                            \
        PH_PRE; MFMAQ(0, 0); PH_POST;                                    \
        /* ph1 */                                                        \
        READ_A4Q(SA, 0, 4);                                              \
        STAGE_HALF2(pa + k2 + 2 * g64, &lds_a[SA2][16384]);              \
        PH_PRE; MFMAQ(4, 0); PH_POST;                                    \
        /* ph2 */                                                        \
        READ_B4(SB, 1, 4);                                               \
        READ_A4Q(SA, 1, 0);                                              \
        PH_PRE; MFMAQ(0, 4); PH_POST;                                    \
        /* ph3 */                                                        \
        READ_A4Q(SA, 1, 4);                                              \
        STAGE_TILE(pb + k2, &lds_b[SB][0]);                              \
        asm volatile("s_waitcnt vmcnt(8)" ::: "memory");                 \
        PH_PRE; MFMAQ(4, 4); PH_POST;                                    \
    }

    // 32 K-tiles; loop covers t = 0..29 (max staged tile index = 31),
    // tiles 30,31 peeled with no stages.
#pragma unroll 1
    for (int t0 = 0; t0 < 30; t0 += 6) {
        DO_TILE(0)
        DO_TILE(1)
        DO_TILE(2)
        DO_TILE(3)
        DO_TILE(4)
        DO_TILE(5)
    }
    // tile 30 (SA=0, SB=0): no stages; gate tile 31 at ph3.
    READ_B4(0, 0, 0);
    READ_A4Q(0, 0, 0);
    PH_PRE; MFMAQ(0, 0); PH_POST;
    READ_A4Q(0, 0, 4);
    PH_PRE; MFMAQ(4, 0); PH_POST;
    READ_B4(0, 1, 4);
    READ_A4Q(0, 1, 0);
    PH_PRE; MFMAQ(0, 4); PH_POST;
    READ_A4Q(0, 1, 4);
    asm volatile("s_waitcnt vmcnt(0)" ::: "memory");  // tile 31 landed
    PH_PRE; MFMAQ(4, 4); PH_POST;
    // tile 31 (SA=1, SB=1): no stages, no gate.
    READ_B4(1, 0, 0);
    READ_A4Q(1, 0, 0);
    PH_PRE; MFMAQ(0, 0); PH_POST;
    READ_A4Q(1, 0, 4);
    PH_PRE; MFMAQ(4, 0); PH_POST;
    READ_B4(1, 1, 4);
    READ_A4Q(1, 1, 0);
    PH_PRE; MFMAQ(0, 4); PH_POST;
    READ_A4Q(1, 1, 4);
    PH_PRE; MFMAQ(4, 4); PH_POST;

    // --- epilogue: dequant + bias (unchanged math/layout) ---
    float wsc[4], bi[4];
#pragma unroll
    for (int j = 0; j < 4; ++j) {
        const int cc = bn * 256 + wn * 64 + j * 16 + l15;
        wsc[j] = wscale[cc];
        bi[j] = bias[cc];
    }
#pragma unroll
    for (int i = 0; i < 8; ++i) {
        const int m0 = bm * 256 + wm * 128 + i * 16 + quad * 4;  // 4-aligned
        const float4 xs4 = *(const float4*)(xscale + m0);
        const float xsv[4] = {xs4.x, xs4.y, xs4.z, xs4.w};
#pragma unroll
        for (int r = 0; r < 4; ++r) {
            const size_t off = (size_t)(m0 + r) * N_DIM + (size_t)bn * 256 + wn * 64 + l15;
#pragma unroll
            for (int j = 0; j < 4; ++j) {
                out[off + j * 16] = (float)acc[i][j][r] * xsv[r] * wsc[j] + bi[j];
            }
        }
    }
}

// ---------------------------------------------------------------------------
extern "C" void kernel_launch(void* const* d_in, const int* in_sizes, int n_in,
                              void* d_out, int out_size, void* d_ws, size_t ws_size,
                              hipStream_t stream) {
    const float* x = (const float*)d_in[0];
    const void* wraw = (const void*)d_in[1];
    const float* wscale = (const float*)d_in[2];
    const float* bias = (const float*)d_in[3];
    float* out = (float*)d_out;

    // workspace layout: [w8: N*K][xq: M*K][xs: M floats]
    int8_t* w8 = (int8_t*)d_ws;
    int8_t* xq = (int8_t*)d_ws + (size_t)N_DIM * K_DIM;
    float* xs = (float*)((char*)d_ws + (size_t)N_DIM * K_DIM + (size_t)M_DIM * K_DIM);

    quant_rows<<<M_DIM, 256, 0, stream>>>(x, xq, xs);
    prep_weight<<<(N_DIM * (K_DIM / 16)) / 256, 256, 0, stream>>>(wraw, w8);
    // 256x256 tiles: 16 x 43 = 688 blocks (1-D, XCD-swizzled)
    w8a8_gemm<<<688, 512, 0, stream>>>(xq, xs, w8, wscale, bias, out);
}

// Round 4
// 490.430 us; speedup vs baseline: 1.0099x; 1.0099x over previous
//
#include <hip/hip_runtime.h>
#include <stdint.h>

#define M_DIM 4096
#define K_DIM 4096
#define N_DIM 11008

typedef int v4i __attribute__((ext_vector_type(4)));

// Address-space casts via uintptr_t (composable_kernel pattern).
#define LDSP(p) ((__attribute__((address_space(3))) void*)(uintptr_t)(p))
#define GLBP(p) ((__attribute__((address_space(1))) void*)(uintptr_t)(p))

// ---------------------------------------------------------------------------
// Kernel 1: per-row dynamic quantization of x (fp32 -> int8) + row scale.
// ---------------------------------------------------------------------------
__global__ __launch_bounds__(256) void quant_rows(const float* __restrict__ x,
                                                  int8_t* __restrict__ xq,
                                                  float* __restrict__ xs_out) {
    const int row = blockIdx.x;
    const int t = threadIdx.x;
    const float4* xr = (const float4*)(x + (size_t)row * K_DIM);

    float4 v[4];
    float amax = 0.0f;
#pragma unroll
    for (int r = 0; r < 4; ++r) {
        v[r] = xr[t + r * 256];
        amax = fmaxf(amax, fmaxf(fmaxf(fabsf(v[r].x), fabsf(v[r].y)),
                                 fmaxf(fabsf(v[r].z), fabsf(v[r].w))));
    }
#pragma unroll
    for (int off = 32; off > 0; off >>= 1)
        amax = fmaxf(amax, __shfl_xor(amax, off));

    __shared__ float smax[4];
    if ((t & 63) == 0) smax[t >> 6] = amax;
    __syncthreads();
    amax = fmaxf(fmaxf(smax[0], smax[1]), fmaxf(smax[2], smax[3]));

    const float xs = fmaxf(amax / 127.0f, 1e-8f);
    if (t == 0) xs_out[row] = xs;

    int* qo = (int*)(xq + (size_t)row * K_DIM);
#pragma unroll
    for (int r = 0; r < 4; ++r) {
        int q0 = (int)rintf(v[r].x / xs);
        int q1 = (int)rintf(v[r].y / xs);
        int q2 = (int)rintf(v[r].z / xs);
        int q3 = (int)rintf(v[r].w / xs);
        q0 = min(127, max(-128, q0));
        q1 = min(127, max(-128, q1));
        q2 = min(127, max(-128, q2));
        q3 = min(127, max(-128, q3));
        int packed = (q0 & 255) | ((q1 & 255) << 8) | ((q2 & 255) << 16) | (q3 << 24);
        qo[t + r * 256] = packed;
    }
}

// ---------------------------------------------------------------------------
// Kernel 2: normalize weight into contiguous int8 in workspace (unchanged).
// ---------------------------------------------------------------------------
__global__ __launch_bounds__(256) void prep_weight(const void* __restrict__ wraw,
                                                   int8_t* __restrict__ w8) {
    const int* wi = (const int*)wraw;
    int c = 0;
#pragma unroll
    for (int i = 0; i < 64; ++i) {
        int w = wi[i];
        c += (w >= -128 && w <= 127) ? 1 : 0;
    }
    const size_t tid = (size_t)blockIdx.x * 256 + threadIdx.x;  // 16 bytes each
    if (c >= 32) {
        union { int4 v; char b[16]; } o;
#pragma unroll
        for (int g = 0; g < 4; ++g) {
            int4 w = ((const int4*)wraw)[tid * 4 + g];
            o.b[g * 4 + 0] = (char)w.x;
            o.b[g * 4 + 1] = (char)w.y;
            o.b[g * 4 + 2] = (char)w.z;
            o.b[g * 4 + 3] = (char)w.w;
        }
        ((int4*)w8)[tid] = o.v;
    } else {
        ((int4*)w8)[tid] = ((const int4*)wraw)[tid];
    }
}

// ---------------------------------------------------------------------------
// Kernel 3: int8 GEMM — 256x256 tile, BK=128, A-ring(3)/B-ring(2) = 160 KiB,
// BARRIER-FREE MID-TILE register software pipeline (1 barrier + 1 vmcnt/tile).
//
// Round-3 post-mortem: with barriers on both sides of every MFMA burst, all
// 8 waves drain the same LDS-port backlog at lgkmcnt(0) and enter MFMA
// together -> LDS port (2300 cy/tile) and matrix pipe (2560 cy/tile) run
// strictly serialized (measured 5300 cy/tile, 43% MfmaUtil), independent of
// phase granularity.
//
// This version removes mid-tile barriers. Per wave, per tile t (slots
// SA=t%3, SB=t%2; register frags afA[4]/afB[4] ping-pong, bf[8]=B(t) both
// k-steps loaded at t-1's tail):
//   S1: stage A(t+2) -> slot (t+2)%3           (safe: its last reads precede
//                                               t-1's publish barrier)
//   R: afB <- A(t,k0,i4-7) | M1: afA x bf[k0] -> acc[0-3] | lgkm(0)
//   R: afA <- A(t,k1,i0-3) | M2: afB x bf[k0] -> acc[4-7] | lgkm(0)
//   R: afB <- A(t,k1,i4-7) | M3: afA x bf[k1] -> acc[0-3] | lgkm(0)
//   vmcnt(4)  [tile t+1 landed: 4 newest in flight = A(t+2)]
//   s_barrier [publish t+1; also orders t-1-tail B(t)-slot reads before S2]
//   S2: stage B(t+2) -> slot t%2  (MUST be after the barrier: other waves
//                                  read this slot at t-1's tail)
//   R: bf[0-3] <- B(t+1,k0), afA <- A(t+1,k0,i0-3)
//   M4: afB x bf[k1] -> acc[4-7]   (overlaps the 12 tail reads)
//   R: bf[4-7] <- B(t+1,k1)        (after M4 in program order; SSA renames)
//   lgkm(0)
// Every lgkmcnt(0) waits on ~4-12 of the wave's own reads (48-144 cy of port
// time) hidden under a 320-640 cy MFMA burst -> LDS port and MFMA pipe now
// run concurrently. Never vmcnt(0) in the loop; tiles 30/31 peeled.
// ---------------------------------------------------------------------------
__global__ __launch_bounds__(512, 2) void w8a8_gemm(const int8_t* __restrict__ xq,
                                                    const float* __restrict__ xscale,
                                                    const int8_t* __restrict__ wgt,
                                                    const float* __restrict__ wscale,
                                                    const float* __restrict__ bias,
                                                    float* __restrict__ out) {
    __shared__ __align__(16) int8_t lds_a[3][32768];  // 96 KB: A ring, 3 tiles
    __shared__ __align__(16) int8_t lds_b[2][32768];  // 64 KB: B ring, 2 tiles

    const int t = threadIdx.x;
    const int lane = t & 63;
    const int wave = t >> 6;   // 0..7
    const int wm = wave >> 2;  // 0..1  (M half)
    const int wn = wave & 3;   // 0..3  (N quarter)
    const int quad = lane >> 4;
    const int l15 = lane & 15;

    // XCD-aware swizzle, bm-fastest within chunk (688 = 8 XCDs x 86).
    const int wg = blockIdx.x;
    const int xcd = wg & 7;
    const int u = wg >> 3;              // 0..85 within XCD
    const int bm = 2 * xcd + (u & 1);   // each XCD owns a bm pair
    const int bn = u >> 1;              // 0..42

    const int8_t* pa = xq + (size_t)bm * 256 * K_DIM;
    const int8_t* pb = wgt + (size_t)bn * 256 * K_DIM;

    // Staging: thread t covers (row = g*64 + (t>>3), 16B-chunk = t&7); source
    // chunk pre-XOR'd so linear LDS write + XOR'd read = swizzle.
    const int srow = t >> 3;  // 0..63
    const size_t soff = (size_t)srow * K_DIM + (size_t)(((t & 7) ^ (srow & 7)) << 4);
    const size_t g64 = (size_t)64 * K_DIM;  // +64 rows

#define STAGE_TILE(gb, lb)                                                                   \
    do {                                                                                     \
        __builtin_amdgcn_global_load_lds(GLBP((gb) + soff), LDSP((lb) + t * 16), 16, 0, 0);  \
        __builtin_amdgcn_global_load_lds(GLBP((gb) + soff + g64), LDSP((lb) + 8192 + t * 16), 16, 0, 0); \
        __builtin_amdgcn_global_load_lds(GLBP((gb) + soff + 2 * g64), LDSP((lb) + 16384 + t * 16), 16, 0, 0); \
        __builtin_amdgcn_global_load_lds(GLBP((gb) + soff + 3 * g64), LDSP((lb) + 24576 + t * 16), 16, 0, 0); \
    } while (0)

    // Fragment read offsets: row*128 + ((ks*4+quad) ^ (row&7))*16.
    int abase[2], bbase[2];
#pragma unroll
    for (int ks = 0; ks < 2; ++ks) {
        const int ar = wm * 128 + l15;
        abase[ks] = ar * 128 + (((ks * 4 + quad) ^ (l15 & 7)) << 4);
        const int br = wn * 64 + l15;
        bbase[ks] = br * 128 + (((ks * 4 + quad) ^ (l15 & 7)) << 4);
    }

    v4i acc[8][4] = {};
    v4i afA[4], afB[4], bf[8];  // bf[0-3]=k0, bf[4-7]=k1 of current tile's B

#define READ_B4(SB, KS, B0)                                           \
    _Pragma("unroll") for (int j = 0; j < 4; ++j)                     \
        bf[(B0) + j] = *(const v4i*)(&lds_b[SB][bbase[KS] + j * 2048]);
#define READ_AQ(DST, SA, KS, I0)                                      \
    _Pragma("unroll") for (int i = 0; i < 4; ++i)                     \
        DST[i] = *(const v4i*)(&lds_a[SA][abase[KS] + ((I0) + i) * 2048]);
#define MFMA4(AF, B0, R0)                                             \
    __builtin_amdgcn_s_setprio(1);                                    \
    _Pragma("unroll") for (int i = 0; i < 4; ++i)                     \
    _Pragma("unroll") for (int j = 0; j < 4; ++j)                     \
        acc[(R0) + i][j] = __builtin_amdgcn_mfma_i32_16x16x64_i8(     \
            AF[i], bf[(B0) + j], acc[(R0) + i][j], 0, 0, 0);          \
    __builtin_amdgcn_s_setprio(0);
#define LGKM0                                                         \
    asm volatile("s_waitcnt lgkmcnt(0)" ::: "memory");                \
    __builtin_amdgcn_sched_barrier(0);

    // ---- prologue: stage tiles 0,1 (A slots 0,1 / B slots 0,1) ----
    STAGE_TILE(pa, &lds_a[0][0]);
    STAGE_TILE(pb, &lds_b[0][0]);
    STAGE_TILE(pa + 128, &lds_a[1][0]);
    STAGE_TILE(pb + 128, &lds_b[1][0]);
    asm volatile("s_waitcnt vmcnt(8)" ::: "memory");  // tile 0 (oldest 8) landed
    __builtin_amdgcn_s_barrier();
    READ_B4(0, 0, 0);      // B(0) k0
    READ_B4(0, 1, 4);      // B(0) k1
    READ_AQ(afA, 0, 0, 0); // A(0,k0,i0-3)
    LGKM0;

#define DO_TILE(U)                                                       \
    {                                                                    \
        constexpr int SA = (U) % 3;                                      \
        constexpr int SB = (U) % 2;                                      \
        constexpr int SA1 = ((U) + 1) % 3;                               \
        constexpr int SB1 = ((U) + 1) % 2;                               \
        constexpr int SA2 = ((U) + 2) % 3;                               \
        const size_t k2 = (size_t)(t0 + (U) + 2) * 128;                  \
        STAGE_TILE(pa + k2, &lds_a[SA2][0]);                             \
        READ_AQ(afB, SA, 0, 4);                                          \
        MFMA4(afA, 0, 0);                                                \
        LGKM0;                                                           \
        READ_AQ(afA, SA, 1, 0);                                          \
        MFMA4(afB, 0, 4);                                                \
        LGKM0;                                                           \
        READ_AQ(afB, SA, 1, 4);                                          \
        MFMA4(afA, 4, 0);                                                \
        LGKM0;                                                           \
        asm volatile("s_waitcnt vmcnt(4)" ::: "memory");                 \
        __builtin_amdgcn_s_barrier();                                    \
        STAGE_TILE(pb + k2, &lds_b[SB][0]);                              \
        READ_B4(SB1, 0, 0);                                              \
        READ_AQ(afA, SA1, 0, 0);                                         \
        MFMA4(afB, 4, 4);                                                \
        READ_B4(SB1, 1, 4);                                              \
        LGKM0;                                                           \
    }

    // 32 K-tiles; loop covers t = 0..29 (max staged tile index = 31),
    // tiles 30,31 peeled with no stages.
#pragma unroll 1
    for (int t0 = 0; t0 < 30; t0 += 6) {
        DO_TILE(0)
        DO_TILE(1)
        DO_TILE(2)
        DO_TILE(3)
        DO_TILE(4)
        DO_TILE(5)
    }
    // ---- tile 30 (SA=0, SB=0, SA1=1, SB1=1): no stages ----
    READ_AQ(afB, 0, 0, 4);
    MFMA4(afA, 0, 0);
    LGKM0;
    READ_AQ(afA, 0, 1, 0);
    MFMA4(afB, 0, 4);
    LGKM0;
    READ_AQ(afB, 0, 1, 4);
    MFMA4(afA, 4, 0);
    LGKM0;
    asm volatile("s_waitcnt vmcnt(0)" ::: "memory");  // B(31) landed
    __builtin_amdgcn_s_barrier();
    READ_B4(1, 0, 0);
    READ_AQ(afA, 1, 0, 0);
    MFMA4(afB, 4, 4);
    READ_B4(1, 1, 4);
    LGKM0;
    // ---- tile 31 (SA=1): final ----
    READ_AQ(afB, 1, 0, 4);
    MFMA4(afA, 0, 0);
    LGKM0;
    READ_AQ(afA, 1, 1, 0);
    MFMA4(afB, 0, 4);
    LGKM0;
    READ_AQ(afB, 1, 1, 4);
    MFMA4(afA, 4, 0);
    LGKM0;
    MFMA4(afB, 4, 4);

    // --- epilogue: dequant + bias (unchanged math/layout) ---
    float wsc[4], bi[4];
#pragma unroll
    for (int j = 0; j < 4; ++j) {
        const int cc = bn * 256 + wn * 64 + j * 16 + l15;
        wsc[j] = wscale[cc];
        bi[j] = bias[cc];
    }
#pragma unroll
    for (int i = 0; i < 8; ++i) {
        const int m0 = bm * 256 + wm * 128 + i * 16 + quad * 4;  // 4-aligned
        const float4 xs4 = *(const float4*)(xscale + m0);
        const float xsv[4] = {xs4.x, xs4.y, xs4.z, xs4.w};
#pragma unroll
        for (int r = 0; r < 4; ++r) {
            const size_t off = (size_t)(m0 + r) * N_DIM + (size_t)bn * 256 + wn * 64 + l15;
#pragma unroll
            for (int j = 0; j < 4; ++j) {
                out[off + j * 16] = (float)acc[i][j][r] * xsv[r] * wsc[j] + bi[j];
            }
        }
    }
}

// ---------------------------------------------------------------------------
extern "C" void kernel_launch(void* const* d_in, const int* in_sizes, int n_in,
                              void* d_out, int out_size, void* d_ws, size_t ws_size,
                              hipStream_t stream) {
    const float* x = (const float*)d_in[0];
    const void* wraw = (const void*)d_in[1];
    const float* wscale = (const float*)d_in[2];
    const float* bias = (const float*)d_in[3];
    float* out = (float*)d_out;

    // workspace layout: [w8: N*K][xq: M*K][xs: M floats]
    int8_t* w8 = (int8_t*)d_ws;
    int8_t* xq = (int8_t*)d_ws + (size_t)N_DIM * K_DIM;
    float* xs = (float*)((char*)d_ws + (size_t)N_DIM * K_DIM + (size_t)M_DIM * K_DIM);

    quant_rows<<<M_DIM, 256, 0, stream>>>(x, xq, xs);
    prep_weight<<<(N_DIM * (K_DIM / 16)) / 256, 256, 0, stream>>>(wraw, w8);
    // 256x256 tiles: 16 x 43 = 688 blocks (1-D, XCD-swizzled)
    w8a8_gemm<<<688, 512, 0, stream>>>(xq, xs, w8, wscale, bias, out);
}